// Round 15
// baseline (54.230 us; speedup 1.0000x reference)
//
#include <hip/hip_runtime.h>
#include <hip/hip_bf16.h>

#define LN_EPS 1e-5f

typedef __attribute__((ext_vector_type(8))) short short8;
typedef __attribute__((ext_vector_type(4))) float floatx4;

static __device__ __forceinline__ unsigned int f2bfu(float f) {
    __hip_bfloat16 h = __float2bfloat16(f);
    return (unsigned int)__builtin_bit_cast(unsigned short, h);
}
static __device__ __forceinline__ float bf2f(unsigned short u) {
    return __builtin_bit_cast(float, (unsigned int)u << 16);
}

// async global->LDS, 16B per lane: LDS dest = wave-uniform base + lane*16,
// global src = per-lane address (m03/m97/m104 semantics).
static __device__ __forceinline__ void gload_lds16(const void* g, void* l) {
    __builtin_amdgcn_global_load_lds(
        (const __attribute__((address_space(1))) void*)g,
        (__attribute__((address_space(3))) void*)l, 16, 0, 0);
}

#define TA_P_STRIDE (257 * 512)   // tableA: [16][257][512] bf16; row 256 = zeros

// ---------------------------------------------------------------------------
// k_prep: blocks 0..511 cast up_w -> wb; 512..639 cast byte_emb -> bb;
// 640..655 zero tableA pad rows; 656..1679 transpose-cast pos_emb -> posT.
// ---------------------------------------------------------------------------
__global__ __launch_bounds__(256) void k_prep(
    const float* __restrict__ up_w, const float* __restrict__ byte_emb,
    const float* __restrict__ pos_emb,
    unsigned short* __restrict__ wb, unsigned short* __restrict__ bb,
    unsigned short* __restrict__ T, unsigned short* __restrict__ PT)
{
    const int b = blockIdx.x;
    if (b < 640) {
        const float* src;
        unsigned short* dst;
        int idx;
        if (b < 512) { src = up_w;     dst = wb; idx = (b * 256 + threadIdx.x) * 4; }
        else         { src = byte_emb; dst = bb; idx = ((b - 512) * 256 + threadIdx.x) * 4; }
        const float4 v = *(const float4*)&src[idx];
        ushort4 o;
        o.x = (unsigned short)f2bfu(v.x); o.y = (unsigned short)f2bfu(v.y);
        o.z = (unsigned short)f2bfu(v.z); o.w = (unsigned short)f2bfu(v.w);
        *(ushort4*)&dst[idx] = o;
    } else if (b < 656) {
        const int p = b - 640;
        if (threadIdx.x < 128) {
            ushort4 z; z.x = z.y = z.z = z.w = 0;
            *(ushort4*)&T[(size_t)p * TA_P_STRIDE + 256 * 512 + threadIdx.x * 4] = z;
        }
    } else {
        // transpose-cast: pos_emb [p][i][j] f32 -> posT [p][j][i] bf16
        const int idx = b - 656;
        const int j0 = (idx & 7) * 64;
        const int i0 = ((idx >> 3) & 7) * 64;
        const int p  = idx >> 6;
        const float* __restrict__ Pp = pos_emb + (size_t)p * 512 * 512;
        unsigned short* __restrict__ Tp = PT + (size_t)p * 512 * 512;

        __shared__ float S[64][65];
        const int r  = threadIdx.x >> 2;
        const int c0 = (threadIdx.x & 3) * 16;

        #pragma unroll
        for (int c = 0; c < 16; c += 4) {
            const float4 v = *(const float4*)&Pp[(size_t)(i0 + r) * 512 + j0 + c0 + c];
            S[r][c0 + c + 0] = v.x;
            S[r][c0 + c + 1] = v.y;
            S[r][c0 + c + 2] = v.z;
            S[r][c0 + c + 3] = v.w;
        }
        __syncthreads();

        #pragma unroll
        for (int h = 0; h < 2; ++h) {
            short8 o;
            #pragma unroll
            for (int k = 0; k < 8; ++k)
                o[k] = (short)f2bfu(S[c0 + h * 8 + k][r]);
            *(short8*)&Tp[(size_t)(j0 + r) * 512 + i0 + c0 + h * 8] = o;
        }
    }
}

// ---------------------------------------------------------------------------
// k1_64: tableA[p][m][j] = sum_i bb[m][i] * posT[p][j][i]  (bf16 out)
// gload_lds 2-phase, BM=128, BN=64, BK=64, 48KB LDS dbuf.
// Grid (8 j, 2 m, 16 p) = 256 blocks (full chip).
// Waves 2x2: wave tile 64m x 32j (acc[4][2]).
// ---------------------------------------------------------------------------
__global__ __launch_bounds__(256) void k1_64(
    const unsigned short* __restrict__ A,   // bb [256][512]
    const unsigned short* __restrict__ PT,  // posT [16][512][512] ([p][j][i])
    unsigned short* __restrict__ T)         // tableA [16][257][512]
{
    const int p  = blockIdx.z;
    const int n0 = blockIdx.x * 64;    // j
    const int m0 = blockIdx.y * 128;   // m
    const unsigned short* __restrict__ Ag = A + (size_t)m0 * 512;
    const unsigned short* __restrict__ Bg = PT + (size_t)p * 512 * 512 + (size_t)n0 * 512;
    unsigned short* __restrict__ Tp = T + (size_t)p * TA_P_STRIDE;

    __shared__ __align__(16) unsigned short SM2[24576];   // 48 KB
    float (*Cst)[68] = (float(*)[68])SM2;

    const int tid = threadIdx.x;
    const int w   = tid >> 6, lane = tid & 63;
    const int lr  = lane & 15, lg = lane >> 4, lk = lg * 8;
    const int wr  = w >> 1, wc = w & 1;
    const int crow = lane >> 3, ccol = (lane & 7) * 8;

    floatx4 acc[4][2] = {};

    #define K1_STAGE(b, kt) do {                                               \
        unsigned short* Ab = SM2 + (b) * 12288;                                \
        unsigned short* Bb = Ab + 8192;                                        \
        _Pragma("unroll")                                                      \
        for (int ci = 0; ci < 4; ++ci) {                                       \
            const int c = w + ci * 4;                                          \
            gload_lds16(&Ag[(size_t)(c * 8 + crow) * 512 + (kt) * 64 + ccol],  \
                        &Ab[c * 512]);                                         \
        }                                                                      \
        _Pragma("unroll")                                                      \
        for (int ci = 0; ci < 2; ++ci) {                                       \
            const int c = w + ci * 4;                                          \
            gload_lds16(&Bg[(size_t)(c * 8 + crow) * 512 + (kt) * 64 + ccol],  \
                        &Bb[c * 512]);                                         \
        }                                                                      \
    } while (0)

    #define K1_COMPUTE(b) do {                                                 \
        const unsigned short* As = SM2 + (b) * 12288;                          \
        const unsigned short* Bs = As + 8192;                                  \
        _Pragma("unroll")                                                      \
        for (int kk = 0; kk < 2; ++kk) {                                       \
            short8 af[4], bf[2];                                               \
            _Pragma("unroll")                                                  \
            for (int mf = 0; mf < 4; ++mf)                                     \
                af[mf] = *(const short8*)&As[(wr * 64 + mf * 16 + lr) * 64 + kk * 32 + lk]; \
            _Pragma("unroll")                                                  \
            for (int nf = 0; nf < 2; ++nf)                                     \
                bf[nf] = *(const short8*)&Bs[(wc * 32 + nf * 16 + lr) * 64 + kk * 32 + lk]; \
            _Pragma("unroll")                                                  \
            for (int mf = 0; mf < 4; ++mf)                                     \
                _Pragma("unroll")                                              \
                for (int nf = 0; nf < 2; ++nf)                                 \
                    acc[mf][nf] = __builtin_amdgcn_mfma_f32_16x16x32_bf16(     \
                        af[mf], bf[nf], acc[mf][nf], 0, 0, 0);                 \
        }                                                                      \
    } while (0)

    K1_STAGE(0, 0);
    __syncthreads();
    {
        int buf = 0;
        for (int kt = 0; kt < 8; ++kt) {
            if (kt < 7) K1_STAGE(buf ^ 1, kt + 1);
            K1_COMPUTE(buf);
            __syncthreads();
            buf ^= 1;
        }
    }
    __syncthreads();   // safe to alias Cst

    #pragma unroll
    for (int qr = 0; qr < 4; ++qr) {
        if (wr == (qr >> 1)) {
            #pragma unroll
            for (int mfq = 0; mfq < 2; ++mfq) {
                const int mf = (qr & 1) * 2 + mfq;
                #pragma unroll
                for (int nf = 0; nf < 2; ++nf)
                    #pragma unroll
                    for (int q = 0; q < 4; ++q)
                        Cst[mfq * 16 + lg * 4 + q][wc * 32 + nf * 16 + lr]
                            = acc[mf][nf][q];
            }
        }
        __syncthreads();
        {
            const int row = tid >> 3;          // 32 rows
            const int c8  = (tid & 7) * 8;     // 8 cols of 8 shorts = 64
            uint4 o;
            o.x = f2bfu(Cst[row][c8 + 0]) | (f2bfu(Cst[row][c8 + 1]) << 16);
            o.y = f2bfu(Cst[row][c8 + 2]) | (f2bfu(Cst[row][c8 + 3]) << 16);
            o.z = f2bfu(Cst[row][c8 + 4]) | (f2bfu(Cst[row][c8 + 5]) << 16);
            o.w = f2bfu(Cst[row][c8 + 6]) | (f2bfu(Cst[row][c8 + 7]) << 16);
            *(uint4*)&Tp[(size_t)(m0 + qr * 32 + row) * 512 + n0 + c8] = o;
        }
        __syncthreads();
    }
    #undef K1_STAGE
    #undef K1_COMPUTE
}

// ---------------------------------------------------------------------------
// k_up97: e2[m][d] = bf16( sum_j e_pre[m][j]*wb[d][j] + up_b[d] )
// gload_lds 2-phase, BM=BN=128, BK=64, 64KB LDS dbuf.
// Grid (8 d-tiles, 64 m-tiles) = 512 blocks, XCD-swizzled: XCD x owns
// m-tiles 8x..8x+7 (rows x*1024..x*1024+1023). e2 stored CACHED.
// ---------------------------------------------------------------------------
__global__ __launch_bounds__(256) void k_up97(
    const unsigned short* __restrict__ Aep,  // e_pre [8192][512]
    const unsigned short* __restrict__ Wb,   // up_w  [1024][512]
    const float* __restrict__ up_b,
    unsigned short* __restrict__ e2)         // [8192][1024] bf16
{
    const int bid = blockIdx.y * 8 + blockIdx.x;
    const int swz = (bid & 7) * 64 + (bid >> 3);
    const int n0 = (swz & 7) * 128;
    const int m0 = (swz >> 3) * 128;
    const unsigned short* __restrict__ Ag = Aep + (size_t)m0 * 512;
    const unsigned short* __restrict__ Bg = Wb + (size_t)n0 * 512;

    __shared__ __align__(16) unsigned short SMEM[32768];   // 64 KB
    float (*Cst)[132] = (float(*)[132])SMEM;

    const int tid = threadIdx.x;
    const int w   = tid >> 6, lane = tid & 63;
    const int lr  = lane & 15, lg = lane >> 4, lk = lg * 8;
    const int wr  = w >> 1, wc = w & 1;
    const int crow = lane >> 3, ccol = (lane & 7) * 8;

    floatx4 acc[4][4] = {};

    #define UP_STAGE(b, kt) do {                                               \
        unsigned short* Ab = SMEM + (b) * 16384;                               \
        unsigned short* Bb = Ab + 8192;                                        \
        _Pragma("unroll")                                                      \
        for (int ci = 0; ci < 4; ++ci) {                                       \
            const int c = w + ci * 4;                                          \
            gload_lds16(&Ag[(size_t)(c * 8 + crow) * 512 + (kt) * 64 + ccol],  \
                        &Ab[c * 512]);                                         \
            gload_lds16(&Bg[(size_t)(c * 8 + crow) * 512 + (kt) * 64 + ccol],  \
                        &Bb[c * 512]);                                         \
        }                                                                      \
    } while (0)

    #define UP_COMPUTE(b) do {                                                 \
        const unsigned short* As = SMEM + (b) * 16384;                         \
        const unsigned short* Bs = As + 8192;                                  \
        _Pragma("unroll")                                                      \
        for (int kk = 0; kk < 2; ++kk) {                                       \
            short8 af[4], bf[4];                                               \
            _Pragma("unroll")                                                  \
            for (int mf = 0; mf < 4; ++mf)                                     \
                af[mf] = *(const short8*)&As[(wr * 64 + mf * 16 + lr) * 64 + kk * 32 + lk]; \
            _Pragma("unroll")                                                  \
            for (int nf = 0; nf < 4; ++nf)                                     \
                bf[nf] = *(const short8*)&Bs[(wc * 64 + nf * 16 + lr) * 64 + kk * 32 + lk]; \
            _Pragma("unroll")                                                  \
            for (int mf = 0; mf < 4; ++mf)                                     \
                _Pragma("unroll")                                              \
                for (int nf = 0; nf < 4; ++nf)                                 \
                    acc[mf][nf] = __builtin_amdgcn_mfma_f32_16x16x32_bf16(     \
                        af[mf], bf[nf], acc[mf][nf], 0, 0, 0);                 \
        }                                                                      \
    } while (0)

    UP_STAGE(0, 0);
    __syncthreads();
    {
        int buf = 0;
        for (int kt = 0; kt < 8; ++kt) {
            if (kt < 7) UP_STAGE(buf ^ 1, kt + 1);
            UP_COMPUTE(buf);
            __syncthreads();
            buf ^= 1;
        }
    }
    __syncthreads();   // safe to alias Cst

    float biasv[4];
    #pragma unroll
    for (int nf = 0; nf < 4; ++nf) biasv[nf] = up_b[n0 + wc * 64 + nf * 16 + lr];

    #pragma unroll
    for (int qr = 0; qr < 4; ++qr) {
        if (wr == (qr >> 1)) {
            #pragma unroll
            for (int mfq = 0; mfq < 2; ++mfq) {
                const int mf = (qr & 1) * 2 + mfq;
                #pragma unroll
                for (int nf = 0; nf < 4; ++nf)
                    #pragma unroll
                    for (int q = 0; q < 4; ++q)
                        Cst[mfq * 16 + lg * 4 + q][wc * 64 + nf * 16 + lr]
                            = acc[mf][nf][q] + biasv[nf];
            }
        }
        __syncthreads();
        #pragma unroll
        for (int pass = 0; pass < 2; ++pass) {
            const int row = pass * 16 + (tid >> 4);
            const int c8  = (tid & 15) * 8;
            uint4 o;
            o.x = f2bfu(Cst[row][c8 + 0]) | (f2bfu(Cst[row][c8 + 1]) << 16);
            o.y = f2bfu(Cst[row][c8 + 2]) | (f2bfu(Cst[row][c8 + 3]) << 16);
            o.z = f2bfu(Cst[row][c8 + 4]) | (f2bfu(Cst[row][c8 + 5]) << 16);
            o.w = f2bfu(Cst[row][c8 + 6]) | (f2bfu(Cst[row][c8 + 7]) << 16);
            *(uint4*)&e2[(size_t)(m0 + qr * 32 + row) * 1024 + n0 + c8] = o;
        }
        __syncthreads();
    }
    #undef UP_STAGE
    #undef UP_COMPUTE
}

// ---------------------------------------------------------------------------
// k_gather: e_pre[row][j] = sum_p tableA[p][idr(row,p)][j].
// Block b (XCD b&7) handles rows (b&7)*1024 + (b>>3)*4 + {0..3} so e_pre rows
// are written on the XCD whose k_up97 blocks will read them (L2-local).
// All 16 table rows preloaded into regs (indep loads), then summed.
// ---------------------------------------------------------------------------
__global__ __launch_bounds__(256) void k_gather(
    const int* __restrict__ ids,
    const unsigned short* __restrict__ T,
    unsigned short* __restrict__ e_pre)
{
    const int b    = blockIdx.x;
    const int row  = (b & 7) * 1024 + (b >> 3) * 4 + (threadIdx.x >> 6);
    const int lane = threadIdx.x & 63;
    const int* __restrict__ idr = ids + row * 16;

    uint4 u[16];
    #pragma unroll
    for (int p = 0; p < 16; ++p) {
        const int id = idr[p];
        const unsigned int off = (unsigned int)((p * 257 + (id < 0 ? 256 : id)) * 512);
        u[p] = *(const uint4*)&T[off + lane * 8];
    }

    float acc[8] = {};
    #pragma unroll
    for (int p = 0; p < 16; ++p) {
        acc[0] += bf2f((unsigned short)(u[p].x & 0xffffu));
        acc[1] += bf2f((unsigned short)(u[p].x >> 16));
        acc[2] += bf2f((unsigned short)(u[p].y & 0xffffu));
        acc[3] += bf2f((unsigned short)(u[p].y >> 16));
        acc[4] += bf2f((unsigned short)(u[p].z & 0xffffu));
        acc[5] += bf2f((unsigned short)(u[p].z >> 16));
        acc[6] += bf2f((unsigned short)(u[p].w & 0xffffu));
        acc[7] += bf2f((unsigned short)(u[p].w >> 16));
    }

    uint4 r;
    r.x = f2bfu(acc[0]) | (f2bfu(acc[1]) << 16);
    r.y = f2bfu(acc[2]) | (f2bfu(acc[3]) << 16);
    r.z = f2bfu(acc[4]) | (f2bfu(acc[5]) << 16);
    r.w = f2bfu(acc[6]) | (f2bfu(acc[7]) << 16);
    *(uint4*)&e_pre[(size_t)row * 512 + lane * 8] = r;
}

// ---------------------------------------------------------------------------
// k_ln: out[row][:] = LN(e2[row][:]) * gamma + beta.  2048 blocks x 4 rows
// sequential; block b -> rows (b&7)*1024 + (b>>3)*4 + r: same XCD as the
// k_up97 writer -> e2 reads are XCD-local L2 hits. out written NT.
// ---------------------------------------------------------------------------
__global__ __launch_bounds__(256) void k_ln(
    const unsigned short* __restrict__ e2,   // [rows][1024] bf16
    const float* __restrict__ gamma,
    const float* __restrict__ beta,
    float* __restrict__ out)                 // [rows][1024] f32
{
    const int b    = blockIdx.x;
    const int base = (b & 7) * 1024 + (b >> 3) * 4;
    const int tid  = threadIdx.x;
    const int wid  = tid >> 6, lane = tid & 63;

    const float4 g  = *(const float4*)&gamma[tid * 4];
    const float4 bt = *(const float4*)&beta[tid * 4];

    __shared__ float red[8];

    for (int r = 0; r < 4; ++r) {
        const int row = base + r;

        const uint2 u = *(const uint2*)&e2[(size_t)row * 1024 + tid * 4];
        const float a0 = bf2f((unsigned short)(u.x & 0xffffu));
        const float a1 = bf2f((unsigned short)(u.x >> 16));
        const float a2 = bf2f((unsigned short)(u.y & 0xffffu));
        const float a3 = bf2f((unsigned short)(u.y >> 16));

        float s  = a0 + a1 + a2 + a3;
        float ss = a0 * a0 + a1 * a1 + a2 * a2 + a3 * a3;
        #pragma unroll
        for (int off = 32; off > 0; off >>= 1) {
            s  += __shfl_down(s,  off, 64);
            ss += __shfl_down(ss, off, 64);
        }

        if (r) __syncthreads();          // protect red from previous read
        if (lane == 0) { red[wid] = s; red[4 + wid] = ss; }
        __syncthreads();

        const float S   = red[0] + red[1] + red[2] + red[3];
        const float SS  = red[4] + red[5] + red[6] + red[7];
        const float mu  = S * (1.0f / 1024.0f);
        const float var = SS * (1.0f / 1024.0f) - mu * mu;
        const float rstd = rsqrtf(var + LN_EPS);

        floatx4 o;
        o[0] = (a0 - mu) * rstd * g.x + bt.x;
        o[1] = (a1 - mu) * rstd * g.y + bt.y;
        o[2] = (a2 - mu) * rstd * g.z + bt.z;
        o[3] = (a3 - mu) * rstd * g.w + bt.w;
        __builtin_nontemporal_store(o, (floatx4*)&out[(size_t)row * 1024 + tid * 4]);
    }
}

extern "C" void kernel_launch(void* const* d_in, const int* in_sizes, int n_in,
                              void* d_out, int out_size, void* d_ws, size_t ws_size,
                              hipStream_t stream) {
    const int*   ids      = (const int*)d_in[0];
    const float* byte_emb = (const float*)d_in[1];
    const float* pos_emb  = (const float*)d_in[2];
    const float* up_w     = (const float*)d_in[3];
    const float* up_b     = (const float*)d_in[4];
    const float* gamma    = (const float*)d_in[5];
    const float* beta     = (const float*)d_in[6];
    float* out = (float*)d_out;

    // ws: wb 1MB | bb 0.25MB | posT 8MB | tableA ~4.2MB | e_pre 8MB | e2 16MB
    unsigned short* wb     = (unsigned short*)d_ws;
    unsigned short* bb     = wb + (size_t)1024 * 512;
    unsigned short* posT   = bb + (size_t)256 * 512;
    unsigned short* tableA = posT + (size_t)16 * 512 * 512;
    unsigned short* e_pre  = tableA + (size_t)16 * TA_P_STRIDE;
    unsigned short* e2     = e_pre + (size_t)8192 * 512;

    const int rows = in_sizes[0] / 16;   // 8192

    k_prep<<<1680, 256, 0, stream>>>(up_w, byte_emb, pos_emb, wb, bb, tableA, posT);

    dim3 g1(8, 2, 16);
    k1_64<<<g1, 256, 0, stream>>>(bb, posT, tableA);

    k_gather<<<rows / 4, 256, 0, stream>>>(ids, tableA, e_pre);

    dim3 g2(8, 64);
    k_up97<<<g2, 256, 0, stream>>>(e_pre, wb, up_b, e2);

    k_ln<<<rows / 4, 256, 0, stream>>>(e2, gamma, beta, out);
}

// Round 16
// 53.579 us; speedup vs baseline: 1.0121x; 1.0121x over previous
//
#include <hip/hip_runtime.h>
#include <hip/hip_bf16.h>

#define LN_EPS 1e-5f

typedef __attribute__((ext_vector_type(8))) short short8;
typedef __attribute__((ext_vector_type(4))) float floatx4;

static __device__ __forceinline__ unsigned int f2bfu(float f) {
    __hip_bfloat16 h = __float2bfloat16(f);
    return (unsigned int)__builtin_bit_cast(unsigned short, h);
}
static __device__ __forceinline__ float bf2f(unsigned short u) {
    return __builtin_bit_cast(float, (unsigned int)u << 16);
}

// async global->LDS, 16B per lane: LDS dest = wave-uniform base + lane*16,
// global src = per-lane address (m03/m97/m104 semantics).
static __device__ __forceinline__ void gload_lds16(const void* g, void* l) {
    __builtin_amdgcn_global_load_lds(
        (const __attribute__((address_space(1))) void*)g,
        (__attribute__((address_space(3))) void*)l, 16, 0, 0);
}

#define TA_P_STRIDE (257 * 512)   // tableA: [16][257][512] bf16; row 256 = zeros

// ---------------------------------------------------------------------------
// k_prep: blocks 0..511 cast up_w -> wb; 512..639 cast byte_emb -> bb;
// 640..655 zero tableA pad rows; 656..1679 transpose-cast pos_emb -> posT.
// ---------------------------------------------------------------------------
__global__ __launch_bounds__(256) void k_prep(
    const float* __restrict__ up_w, const float* __restrict__ byte_emb,
    const float* __restrict__ pos_emb,
    unsigned short* __restrict__ wb, unsigned short* __restrict__ bb,
    unsigned short* __restrict__ T, unsigned short* __restrict__ PT)
{
    const int b = blockIdx.x;
    if (b < 640) {
        const float* src;
        unsigned short* dst;
        int idx;
        if (b < 512) { src = up_w;     dst = wb; idx = (b * 256 + threadIdx.x) * 4; }
        else         { src = byte_emb; dst = bb; idx = ((b - 512) * 256 + threadIdx.x) * 4; }
        const float4 v = *(const float4*)&src[idx];
        ushort4 o;
        o.x = (unsigned short)f2bfu(v.x); o.y = (unsigned short)f2bfu(v.y);
        o.z = (unsigned short)f2bfu(v.z); o.w = (unsigned short)f2bfu(v.w);
        *(ushort4*)&dst[idx] = o;
    } else if (b < 656) {
        const int p = b - 640;
        if (threadIdx.x < 128) {
            ushort4 z; z.x = z.y = z.z = z.w = 0;
            *(ushort4*)&T[(size_t)p * TA_P_STRIDE + 256 * 512 + threadIdx.x * 4] = z;
        }
    } else {
        // transpose-cast: pos_emb [p][i][j] f32 -> posT [p][j][i] bf16
        const int idx = b - 656;
        const int j0 = (idx & 7) * 64;
        const int i0 = ((idx >> 3) & 7) * 64;
        const int p  = idx >> 6;
        const float* __restrict__ Pp = pos_emb + (size_t)p * 512 * 512;
        unsigned short* __restrict__ Tp = PT + (size_t)p * 512 * 512;

        __shared__ float S[64][65];
        const int r  = threadIdx.x >> 2;
        const int c0 = (threadIdx.x & 3) * 16;

        #pragma unroll
        for (int c = 0; c < 16; c += 4) {
            const float4 v = *(const float4*)&Pp[(size_t)(i0 + r) * 512 + j0 + c0 + c];
            S[r][c0 + c + 0] = v.x;
            S[r][c0 + c + 1] = v.y;
            S[r][c0 + c + 2] = v.z;
            S[r][c0 + c + 3] = v.w;
        }
        __syncthreads();

        #pragma unroll
        for (int h = 0; h < 2; ++h) {
            short8 o;
            #pragma unroll
            for (int k = 0; k < 8; ++k)
                o[k] = (short)f2bfu(S[c0 + h * 8 + k][r]);
            *(short8*)&Tp[(size_t)(j0 + r) * 512 + i0 + c0 + h * 8] = o;
        }
    }
}

// ---------------------------------------------------------------------------
// gload_lds 2-phase GEMM template. Block 256 thr = 4 waves (2x2), BM=BN=128,
// BK=64, operands K-major (row stride 512). LDS: 2 buffers x (A 16KB + B 16KB)
// = 64KB, LINEAR layout. Per iter: STAGE(next buf), COMPUTE(cur buf), ONE
// __syncthreads. Epilogue: Cst LDS staging -> full-row coalesced stores.
// ---------------------------------------------------------------------------
#define GEMM_PROLOG()                                                          \
    __shared__ __align__(16) unsigned short SMEM[32768]; /* 64 KB */           \
    float (*Cst)[132] = (float(*)[132])SMEM;                                   \
    const int tid = threadIdx.x;                                               \
    const int w   = tid >> 6, lane = tid & 63;                                 \
    const int lr  = lane & 15, lg = lane >> 4, lk = lg * 8;                    \
    const int wr  = w >> 1, wc = w & 1;                                        \
    const int crow = lane >> 3, ccol = (lane & 7) * 8;                         \
    floatx4 acc[4][4] = {};

#define GEMM_STAGE(b, kt) do {                                                 \
    unsigned short* Ab = SMEM + (b) * 16384;                                   \
    unsigned short* Bb = Ab + 8192;                                            \
    _Pragma("unroll")                                                          \
    for (int ci = 0; ci < 4; ++ci) {                                           \
        const int c = w + ci * 4;                                              \
        gload_lds16(&Ag[(size_t)(c * 8 + crow) * 512 + (kt) * 64 + ccol],      \
                    &Ab[c * 512]);                                             \
        gload_lds16(&Bg[(size_t)(c * 8 + crow) * 512 + (kt) * 64 + ccol],      \
                    &Bb[c * 512]);                                             \
    }                                                                          \
} while (0)

#define GEMM_COMPUTE(b) do {                                                   \
    const unsigned short* As = SMEM + (b) * 16384;                             \
    const unsigned short* Bs = As + 8192;                                      \
    _Pragma("unroll")                                                          \
    for (int kk = 0; kk < 2; ++kk) {                                           \
        short8 af[4], bf[4];                                                   \
        _Pragma("unroll")                                                      \
        for (int mf = 0; mf < 4; ++mf)                                         \
            af[mf] = *(const short8*)&As[(wr * 64 + mf * 16 + lr) * 64 + kk * 32 + lk]; \
        _Pragma("unroll")                                                      \
        for (int nf = 0; nf < 4; ++nf)                                         \
            bf[nf] = *(const short8*)&Bs[(wc * 64 + nf * 16 + lr) * 64 + kk * 32 + lk]; \
        _Pragma("unroll")                                                      \
        for (int mf = 0; mf < 4; ++mf)                                         \
            _Pragma("unroll")                                                  \
            for (int nf = 0; nf < 4; ++nf)                                     \
                acc[mf][nf] = __builtin_amdgcn_mfma_f32_16x16x32_bf16(         \
                    af[mf], bf[nf], acc[mf][nf], 0, 0, 0);                     \
    }                                                                          \
} while (0)

#define GEMM_MAIN()                                                            \
    GEMM_STAGE(0, 0);                                                          \
    __syncthreads();                                                           \
    {                                                                          \
        int buf = 0;                                                           \
        for (int kt = 0; kt < 8; ++kt) {                                       \
            if (kt < 7) GEMM_STAGE(buf ^ 1, kt + 1);                           \
            GEMM_COMPUTE(buf);                                                 \
            __syncthreads();                                                   \
            buf ^= 1;                                                          \
        }                                                                      \
    }

// Stage one 32-row quarter of acc (+per-col add 'addv') into Cst.
#define CST_STAGE(qr, addv)                                                    \
    if (wr == ((qr) >> 1)) {                                                   \
        _Pragma("unroll")                                                      \
        for (int mfq = 0; mfq < 2; ++mfq) {                                    \
            const int mf = ((qr) & 1) * 2 + mfq;                               \
            _Pragma("unroll")                                                  \
            for (int nf = 0; nf < 4; ++nf)                                     \
                _Pragma("unroll")                                              \
                for (int q = 0; q < 4; ++q)                                    \
                    Cst[mfq * 16 + lg * 4 + q][wc * 64 + nf * 16 + lr]         \
                        = acc[mf][nf][q] + addv;                               \
        }                                                                      \
    }

// ---------------------------------------------------------------------------
// k1_97: tableA[p][m][j] = sum_i bb[m][i] * posT[p][j][i]  (bf16 out)
// Grid (4 j-tiles, 2 m-tiles, 16 p) = 128 blocks.
// ---------------------------------------------------------------------------
__global__ __launch_bounds__(256) void k1_97(
    const unsigned short* __restrict__ A,   // bb [256][512]
    const unsigned short* __restrict__ PT,  // posT [16][512][512] ([p][j][i])
    unsigned short* __restrict__ T)         // tableA [16][257][512]
{
    const int p  = blockIdx.z;
    const int n0 = blockIdx.x * 128;   // j
    const int m0 = blockIdx.y * 128;   // m
    const unsigned short* __restrict__ Ag = A + (size_t)m0 * 512;
    const unsigned short* __restrict__ Bg = PT + (size_t)p * 512 * 512 + (size_t)n0 * 512;
    unsigned short* __restrict__ Tp = T + (size_t)p * TA_P_STRIDE;

    GEMM_PROLOG();
    GEMM_MAIN();
    __syncthreads();   // all LDS frag reads done; safe to alias Cst

    #pragma unroll
    for (int qr = 0; qr < 4; ++qr) {
        CST_STAGE(qr, 0.0f);
        __syncthreads();
        #pragma unroll
        for (int pass = 0; pass < 2; ++pass) {
            const int row = pass * 16 + (tid >> 4);
            const int c8  = (tid & 15) * 8;
            uint4 o;
            o.x = f2bfu(Cst[row][c8 + 0]) | (f2bfu(Cst[row][c8 + 1]) << 16);
            o.y = f2bfu(Cst[row][c8 + 2]) | (f2bfu(Cst[row][c8 + 3]) << 16);
            o.z = f2bfu(Cst[row][c8 + 4]) | (f2bfu(Cst[row][c8 + 5]) << 16);
            o.w = f2bfu(Cst[row][c8 + 6]) | (f2bfu(Cst[row][c8 + 7]) << 16);
            *(uint4*)&Tp[(size_t)(m0 + qr * 32 + row) * 512 + n0 + c8] = o;
        }
        __syncthreads();
    }
}

// ---------------------------------------------------------------------------
// k_up97: e2[m][d] = bf16( sum_j e_pre[m][j]*wb[d][j] + up_b[d] )
// Grid (8 d-tiles, 64 m-tiles) = 512 blocks, XCD-swizzled: XCD x owns
// m-tiles 8x..8x+7 (rows x*1024..x*1024+1023). e2 stored CACHED (re-read by
// k_ln on the same XCD).
// ---------------------------------------------------------------------------
__global__ __launch_bounds__(256) void k_up97(
    const unsigned short* __restrict__ Aep,  // e_pre [8192][512]
    const unsigned short* __restrict__ Wb,   // up_w  [1024][512]
    const float* __restrict__ up_b,
    unsigned short* __restrict__ e2)         // [8192][1024] bf16
{
    const int bid = blockIdx.y * 8 + blockIdx.x;
    const int swz = (bid & 7) * 64 + (bid >> 3);
    const int n0 = (swz & 7) * 128;
    const int m0 = (swz >> 3) * 128;
    const unsigned short* __restrict__ Ag = Aep + (size_t)m0 * 512;
    const unsigned short* __restrict__ Bg = Wb + (size_t)n0 * 512;

    GEMM_PROLOG();
    GEMM_MAIN();
    __syncthreads();   // all LDS frag reads done; safe to alias Cst

    float biasv[4];
    #pragma unroll
    for (int nf = 0; nf < 4; ++nf) biasv[nf] = up_b[n0 + wc * 64 + nf * 16 + lr];

    #pragma unroll
    for (int qr = 0; qr < 4; ++qr) {
        CST_STAGE(qr, biasv[nf]);
        __syncthreads();
        #pragma unroll
        for (int pass = 0; pass < 2; ++pass) {
            const int row = pass * 16 + (tid >> 4);
            const int c8  = (tid & 15) * 8;
            uint4 o;
            o.x = f2bfu(Cst[row][c8 + 0]) | (f2bfu(Cst[row][c8 + 1]) << 16);
            o.y = f2bfu(Cst[row][c8 + 2]) | (f2bfu(Cst[row][c8 + 3]) << 16);
            o.z = f2bfu(Cst[row][c8 + 4]) | (f2bfu(Cst[row][c8 + 5]) << 16);
            o.w = f2bfu(Cst[row][c8 + 6]) | (f2bfu(Cst[row][c8 + 7]) << 16);
            *(uint4*)&e2[(size_t)(m0 + qr * 32 + row) * 1024 + n0 + c8] = o;
        }
        __syncthreads();
    }
}

// ---------------------------------------------------------------------------
// k_gather: e_pre[row][j] = sum_p tableA[p][idr(row,p)][j].
// Block b (XCD b&7) handles rows (b&7)*1024 + (b>>3)*4 + {0..3} so e_pre rows
// are written on the XCD whose k_up97 blocks will read them (L2-local).
// All 16 table rows preloaded into regs (indep loads), then summed.
// ---------------------------------------------------------------------------
__global__ __launch_bounds__(256) void k_gather(
    const int* __restrict__ ids,
    const unsigned short* __restrict__ T,
    unsigned short* __restrict__ e_pre)
{
    const int b    = blockIdx.x;
    const int row  = (b & 7) * 1024 + (b >> 3) * 4 + (threadIdx.x >> 6);
    const int lane = threadIdx.x & 63;
    const int* __restrict__ idr = ids + row * 16;

    uint4 u[16];
    #pragma unroll
    for (int p = 0; p < 16; ++p) {
        const int id = idr[p];
        const unsigned int off = (unsigned int)((p * 257 + (id < 0 ? 256 : id)) * 512);
        u[p] = *(const uint4*)&T[off + lane * 8];
    }

    float acc[8] = {};
    #pragma unroll
    for (int p = 0; p < 16; ++p) {
        acc[0] += bf2f((unsigned short)(u[p].x & 0xffffu));
        acc[1] += bf2f((unsigned short)(u[p].x >> 16));
        acc[2] += bf2f((unsigned short)(u[p].y & 0xffffu));
        acc[3] += bf2f((unsigned short)(u[p].y >> 16));
        acc[4] += bf2f((unsigned short)(u[p].z & 0xffffu));
        acc[5] += bf2f((unsigned short)(u[p].z >> 16));
        acc[6] += bf2f((unsigned short)(u[p].w & 0xffffu));
        acc[7] += bf2f((unsigned short)(u[p].w >> 16));
    }

    uint4 r;
    r.x = f2bfu(acc[0]) | (f2bfu(acc[1]) << 16);
    r.y = f2bfu(acc[2]) | (f2bfu(acc[3]) << 16);
    r.z = f2bfu(acc[4]) | (f2bfu(acc[5]) << 16);
    r.w = f2bfu(acc[6]) | (f2bfu(acc[7]) << 16);
    *(uint4*)&e_pre[(size_t)row * 512 + lane * 8] = r;
}

// ---------------------------------------------------------------------------
// k_ln: out[row][:] = LN(e2[row][:]) * gamma + beta.  Block b -> row
// (b&7)*1024 + (b>>3): same XCD as the k_up97 block that wrote the row ->
// e2 read is an XCD-local L2 hit. out written NT (never re-read).
// ---------------------------------------------------------------------------
__global__ __launch_bounds__(256) void k_ln(
    const unsigned short* __restrict__ e2,   // [rows][1024] bf16
    const float* __restrict__ gamma,
    const float* __restrict__ beta,
    float* __restrict__ out)                 // [rows][1024] f32
{
    const int b   = blockIdx.x;
    const int row = (b & 7) * 1024 + (b >> 3);
    const int tid = threadIdx.x;

    const uint2 u = *(const uint2*)&e2[(size_t)row * 1024 + tid * 4];
    float a0 = bf2f((unsigned short)(u.x & 0xffffu));
    float a1 = bf2f((unsigned short)(u.x >> 16));
    float a2 = bf2f((unsigned short)(u.y & 0xffffu));
    float a3 = bf2f((unsigned short)(u.y >> 16));

    float s  = a0 + a1 + a2 + a3;
    float ss = a0 * a0 + a1 * a1 + a2 * a2 + a3 * a3;
    #pragma unroll
    for (int off = 32; off > 0; off >>= 1) {
        s  += __shfl_down(s,  off, 64);
        ss += __shfl_down(ss, off, 64);
    }

    __shared__ float red[8];
    const int wid = tid >> 6, lane = tid & 63;
    if (lane == 0) { red[wid] = s; red[4 + wid] = ss; }
    __syncthreads();

    const float S   = red[0] + red[1] + red[2] + red[3];
    const float SS  = red[4] + red[5] + red[6] + red[7];
    const float mu  = S * (1.0f / 1024.0f);
    const float var = SS * (1.0f / 1024.0f) - mu * mu;
    const float rstd = rsqrtf(var + LN_EPS);

    const float4 g = *(const float4*)&gamma[tid * 4];
    const float4 bt = *(const float4*)&beta[tid * 4];
    floatx4 o;
    o[0] = (a0 - mu) * rstd * g.x + bt.x;
    o[1] = (a1 - mu) * rstd * g.y + bt.y;
    o[2] = (a2 - mu) * rstd * g.z + bt.z;
    o[3] = (a3 - mu) * rstd * g.w + bt.w;
    __builtin_nontemporal_store(o, (floatx4*)&out[(size_t)row * 1024 + tid * 4]);
}

extern "C" void kernel_launch(void* const* d_in, const int* in_sizes, int n_in,
                              void* d_out, int out_size, void* d_ws, size_t ws_size,
                              hipStream_t stream) {
    const int*   ids      = (const int*)d_in[0];
    const float* byte_emb = (const float*)d_in[1];
    const float* pos_emb  = (const float*)d_in[2];
    const float* up_w     = (const float*)d_in[3];
    const float* up_b     = (const float*)d_in[4];
    const float* gamma    = (const float*)d_in[5];
    const float* beta     = (const float*)d_in[6];
    float* out = (float*)d_out;

    // ws: wb 1MB | bb 0.25MB | posT 8MB | tableA ~4.2MB | e_pre 8MB | e2 16MB
    unsigned short* wb     = (unsigned short*)d_ws;
    unsigned short* bb     = wb + (size_t)1024 * 512;
    unsigned short* posT   = bb + (size_t)256 * 512;
    unsigned short* tableA = posT + (size_t)16 * 512 * 512;
    unsigned short* e_pre  = tableA + (size_t)16 * TA_P_STRIDE;
    unsigned short* e2     = e_pre + (size_t)8192 * 512;

    const int rows = in_sizes[0] / 16;   // 8192

    k_prep<<<1680, 256, 0, stream>>>(up_w, byte_emb, pos_emb, wb, bb, tableA, posT);

    dim3 g1(4, 2, 16);
    k1_97<<<g1, 256, 0, stream>>>(bb, posT, tableA);

    k_gather<<<rows / 4, 256, 0, stream>>>(ids, tableA, e_pre);

    dim3 g2(8, 64);
    k_up97<<<g2, 256, 0, stream>>>(e_pre, wb, up_b, e2);

    k_ln<<<rows, 256, 0, stream>>>(e2, gamma, beta, out);
}